// Round 5
// baseline (988.049 us; speedup 1.0000x reference)
//
#include <hip/hip_runtime.h>
#include <hip/hip_bf16.h>
#include <math.h>

// Decoder_62234076119175 — round 5: register-tiled draft scoring + LDS redis.
// Draft/top-k path stays f32 end-to-end (discrete selection must match numpy).

typedef unsigned short u16;
using bf16x8 = __attribute__((ext_vector_type(8))) short;
using f32x4  = __attribute__((ext_vector_type(4))) float;

#define NEGBIG -1e30f

__device__ __forceinline__ unsigned int fkey(float f) {
    unsigned int u = __float_as_uint(f);
    return (u & 0x80000000u) ? ~u : (u | 0x80000000u);
}

__device__ __forceinline__ u16 f2b(float f) {
    union { float f; unsigned u; } x; x.f = f;
    unsigned r = x.u + 0x7fffu + ((x.u >> 16) & 1u);  // RNE
    return (u16)(r >> 16);
}

__device__ __forceinline__ void gl_lds16(const u16* g, u16* l) {
    __builtin_amdgcn_global_load_lds(
        (__attribute__((address_space(1))) void*)(g),
        (__attribute__((address_space(3))) void*)(l), 16, 0, 0);
}

// ---------------- RoPE tables ----------------
__global__ void rope_tables_kernel(float* __restrict__ cosb, float* __restrict__ sinb) {
    int t = blockIdx.x;
    int i = threadIdx.x; // 0..63
    double inv = pow(10000.0, -((double)(2 * i)) / 128.0);
    double ang = (double)t * inv;
    cosb[t * 64 + i] = (float)cos(ang);
    sinb[t * 64 + i] = (float)sin(ang);
}

// ---------------- f32 -> bf16 elementwise (hs) ----------------
__global__ __launch_bounds__(256) void conv_bf16_kernel(const float* __restrict__ in, u16* __restrict__ out) {
    int i = blockIdx.x * 256 + threadIdx.x;
    float4 v = ((const float4*)in)[i];
    u16 o[4] = {f2b(v.x), f2b(v.y), f2b(v.z), f2b(v.w)};
    ((uint2*)out)[i] = *(const uint2*)o;
}

// ---------------- f32 [K][N] -> bf16 [N][K] transpose ----------------
__global__ __launch_bounds__(256) void transpose_bf16_kernel(
    const float* __restrict__ in, u16* __restrict__ out, int Kdim, int N)
{
    __shared__ u16 tile[64][66];
    int n0 = blockIdx.x * 64, k0 = blockIdx.y * 64;
    int t = threadIdx.x;
#pragma unroll
    for (int u = 0; u < 16; ++u) {
        int e = u * 256 + t; int r = e >> 6, c = e & 63;
        tile[r][c] = f2b(in[(size_t)(k0 + r) * N + n0 + c]);
    }
    __syncthreads();
#pragma unroll
    for (int u = 0; u < 16; ++u) {
        int e = u * 256 + t; int r = e >> 6, c = e & 63;
        out[(size_t)(n0 + r) * Kdim + k0 + c] = tile[c][r];
    }
}

// ---------------- RoPE apply + scale + bf16 pack: [s][W] -> [h][s][128] ----
__global__ __launch_bounds__(128) void rope_pack_kernel(
    const float* __restrict__ src, int W, const float* __restrict__ cosb,
    const float* __restrict__ sinb, u16* __restrict__ dst, float scale)
{
    int s = blockIdx.x, h = blockIdx.y, d = threadIdx.x;
    float x  = src[(size_t)s * W + h * 128 + d];
    float x2 = src[(size_t)s * W + h * 128 + (d ^ 64)];
    float cs = cosb[s * 64 + (d & 63)];
    float sn = sinb[s * 64 + (d & 63)];
    float rot = (d < 64) ? -x2 : x2;
    dst[((size_t)h * 1024 + s) * 128 + d] = f2b((x * cs + rot * sn) * scale);
}

// ---------------- bf16 MFMA GEMM: C[M][N] f32 = A[M][K] x BT[N][K] ----------
__device__ __forceinline__ void gemm_bf16_tile(
    const u16* __restrict__ A, const u16* __restrict__ BT, float* __restrict__ C,
    int Kdim, int Ncols, int bm, int bn)
{
    __shared__ u16 As[128 * 32];
    __shared__ u16 Bs[128 * 32];
    const int t = threadIdx.x;
    const int wave = t >> 6, lane = t & 63;
    const int wr = wave >> 1, wc = wave & 1;
    const int fr = lane & 15, fq = lane >> 4;

    f32x4 acc[4][4];
#pragma unroll
    for (int m = 0; m < 4; ++m)
#pragma unroll
        for (int n = 0; n < 4; ++n) acc[m][n] = 0.f;

    const int srow = 32 * wave + (lane >> 2);
    const int skc = (lane & 3) * 8;
    const u16* aS = A  + ((size_t)(bm * 128) + srow) * Kdim + skc;
    const u16* bS = BT + ((size_t)(bn * 128) + srow) * Kdim + skc;
    u16* aD0 = As + 1024 * wave;  u16* aD1 = aD0 + 512;
    u16* bD0 = Bs + 1024 * wave;  u16* bD1 = bD0 + 512;

    const int aoff = (wr * 64 + fr) * 32 + fq * 8;
    const int boff = (wc * 64 + fr) * 32 + fq * 8;

    for (int k0 = 0; k0 < Kdim; k0 += 32) {
        __syncthreads();
        gl_lds16(aS + k0, aD0);
        gl_lds16(aS + (size_t)16 * Kdim + k0, aD1);
        gl_lds16(bS + k0, bD0);
        gl_lds16(bS + (size_t)16 * Kdim + k0, bD1);
        __syncthreads();

        bf16x8 af[4], bfr[4];
#pragma unroll
        for (int m = 0; m < 4; ++m) af[m] = *(const bf16x8*)(As + aoff + m * 512);
#pragma unroll
        for (int n = 0; n < 4; ++n) bfr[n] = *(const bf16x8*)(Bs + boff + n * 512);
#pragma unroll
        for (int m = 0; m < 4; ++m)
#pragma unroll
            for (int n = 0; n < 4; ++n)
                acc[m][n] = __builtin_amdgcn_mfma_f32_16x16x32_bf16(af[m], bfr[n], acc[m][n], 0, 0, 0);
    }

    float* Cb = C + (size_t)(bm * 128 + wr * 64 + fq * 4) * Ncols + bn * 128 + wc * 64 + fr;
#pragma unroll
    for (int m = 0; m < 4; ++m)
#pragma unroll
        for (int j = 0; j < 4; ++j)
#pragma unroll
            for (int n = 0; n < 4; ++n)
                Cb[(size_t)(m * 16 + j) * Ncols + n * 16] = acc[m][n][j];
}

__global__ __launch_bounds__(256) void gemm_qkv_bf16_kernel(
    const u16* __restrict__ hs_bf, const u16* __restrict__ wqT,
    const u16* __restrict__ wkT, const u16* __restrict__ wvT,
    float* __restrict__ q, float* __restrict__ k, float* __restrict__ v)
{
    int bn = blockIdx.x, bm = blockIdx.y;
    const u16* Bsel; float* Csel; int Ncols;
    if (bn < 32)      { Bsel = wqT; Csel = q; Ncols = 4096; }
    else if (bn < 40) { Bsel = wkT; Csel = k; Ncols = 1024; bn -= 32; }
    else              { Bsel = wvT; Csel = v; Ncols = 1024; bn -= 40; }
    gemm_bf16_tile(hs_bf, Bsel, Csel, 4096, Ncols, bm, bn);
}

__global__ __launch_bounds__(256) void gemm_wo_bf16_kernel(
    const u16* __restrict__ attn_bf, const u16* __restrict__ woT, float* __restrict__ out)
{
    gemm_bf16_tile(attn_bf, woT, out, 4096, 4096, blockIdx.y, blockIdx.x);
}

// ---------------- lrq/lrk = hs @ mixq / mixk (f32, exact path) -------------
__global__ __launch_bounds__(256) void lr_kernel(
    const float* __restrict__ hs, const float* __restrict__ mixq, const float* __restrict__ mixk,
    float* __restrict__ lrq, float* __restrict__ lrk)
{
    __shared__ float row[4096];
    __shared__ float part[2][32][4];
    int m = blockIdx.x, t = threadIdx.x;
#pragma unroll
    for (int u = 0; u < 4; ++u)
        ((float4*)row)[t + u * 256] = ((const float4*)(hs + (size_t)m * 4096))[t + u * 256];
    __syncthreads();
    int r = t & 31, which = (t >> 5) & 1, quarter = t >> 6;
    const float* mix = which ? mixk : mixq;
    float acc = 0.f;
    int kbase = quarter * 1024;
#pragma unroll 8
    for (int kk = 0; kk < 1024; ++kk)
        acc = fmaf(row[kbase + kk], mix[(size_t)(kbase + kk) * 32 + r], acc);
    part[which][r][quarter] = acc;
    __syncthreads();
    if (t < 64) {
        int r2 = t & 31, w2 = t >> 5;
        float s = part[w2][r2][0] + part[w2][r2][1] + part[w2][r2][2] + part[w2][r2][3];
        (w2 ? lrk : lrq)[(size_t)m * 32 + r2] = s;
    }
}

// ---------------- pq/pk[h][m][d] = sum_r lr[m][r] * pos[m][h][r][d] --------
__global__ __launch_bounds__(128) void ppos_kernel(
    const float* __restrict__ lr, const float* __restrict__ pos, float* __restrict__ out)
{
    int h = blockIdx.x, m = blockIdx.y, d = threadIdx.x;
    __shared__ float lrs[32];
    if (d < 32) lrs[d] = lr[(size_t)m * 32 + d];
    __syncthreads();
    const float* base = pos + ((size_t)(m * 32 + h) * 32) * 128 + d;
    float acc = 0.f;
#pragma unroll
    for (int r = 0; r < 32; ++r)
        acc = fmaf(lrs[r], base[(size_t)r * 128], acc);
    out[((size_t)h * 1024 + m) * 128 + d] = acc;
}

// ---------------- draft score (register-tiled) + exact top-512 select ------
// Phase 1 (scoring): threads = (qid=t>>6)x(kvid=t&63); 4q x 4kv register tile.
//   pq reads are wave-uniform broadcasts (qid == wave id); pk slab staged
//   [256 cols][pitch 36] (16B-aligned, even bank demand).
// Phase 2 (select): threads = (i=t>>4, jj=t&15); unchanged radix select over
//   64 keys/thread picked up from the LDS redis buffer (aliases stage).
__global__ __launch_bounds__(256, 2) void draft_select_kernel(
    const float* __restrict__ pq, const float* __restrict__ pk,
    unsigned long long* __restrict__ mask)
{
    int qt = blockIdx.x, h = blockIdx.y;
    int q0 = qt * 16;
    int t = threadIdx.x;

    __shared__ float pqs[16][132];
    __shared__ float stage[256 * 36];   // pk slab; aliased as redis[16][257]

    const float* pqh = pq + ((size_t)h * 1024 + q0) * 128;
    const float* pkh = pk + (size_t)h * 1024 * 128;

#pragma unroll
    for (int u = 0; u < 2; ++u) {
        int e = t + u * 256;
        int row = e >> 5, dg = (e & 31) * 4;
        *(float4*)(&pqs[row][dg]) = *(const float4*)(pqh + (size_t)row * 128 + dg);
    }
    // (first __syncthreads inside the slab loop orders pqs writes vs reads)

    const int qid = t >> 6;        // == wave id
    const int kvid = t & 63;
    const int i = t >> 4, jj = t & 15;
    const int qrow = q0 + i;

    unsigned int vals[64];

    for (int cc = 0; cc < 4; ++cc) {
        int kv0 = cc * 256;
        float acc[4][4];
#pragma unroll
        for (int qq = 0; qq < 4; ++qq)
#pragma unroll
            for (int cw = 0; cw < 4; ++cw) acc[qq][cw] = 0.f;

        for (int slab = 0; slab < 4; ++slab) {
            int d0 = slab * 32;
            __syncthreads();
#pragma unroll
            for (int u = 0; u < 8; ++u) {
                int e = t + u * 256;
                int row = e >> 3, f4 = (e & 7) * 4;
                *(float4*)(&stage[row * 36 + f4]) =
                    *(const float4*)(pkh + (size_t)(kv0 + row) * 128 + d0 + f4);
            }
            __syncthreads();
#pragma unroll
            for (int dg = 0; dg < 8; ++dg) {
                float4 a[4], b[4];
#pragma unroll
                for (int qq = 0; qq < 4; ++qq)
                    a[qq] = *(const float4*)(&pqs[qid * 4 + qq][d0 + dg * 4]);
#pragma unroll
                for (int cw = 0; cw < 4; ++cw)
                    b[cw] = *(const float4*)(&stage[(kvid + 64 * cw) * 36 + dg * 4]);
#pragma unroll
                for (int qq = 0; qq < 4; ++qq)
#pragma unroll
                    for (int cw = 0; cw < 4; ++cw) {
                        acc[qq][cw] = fmaf(a[qq].x, b[cw].x, acc[qq][cw]);
                        acc[qq][cw] = fmaf(a[qq].y, b[cw].y, acc[qq][cw]);
                        acc[qq][cw] = fmaf(a[qq].z, b[cw].z, acc[qq][cw]);
                        acc[qq][cw] = fmaf(a[qq].w, b[cw].w, acc[qq][cw]);
                    }
            }
        }
        __syncthreads();
        float* redis = stage;   // [16][257]
#pragma unroll
        for (int qq = 0; qq < 4; ++qq)
#pragma unroll
            for (int cw = 0; cw < 4; ++cw)
                redis[(qid * 4 + qq) * 257 + kvid + 64 * cw] = acc[qq][cw];
        __syncthreads();
#pragma unroll
        for (int m = 0; m < 16; ++m) {
            int col = jj + 16 * m;
            float s = redis[i * 257 + col];
            vals[cc * 16 + m] = fkey((kv0 + col) <= qrow ? s : NEGBIG);
        }
    }

    // radix select the 512-th largest key of this row (16 lanes cooperate)
    unsigned int p = 0u;
    int kth = 512;
    for (int b = 31; b >= 0; --b) {
        unsigned int bit = 1u << b;
        unsigned int himask = (b == 31) ? 0u : (0xFFFFFFFFu << (b + 1));
        int cnt = 0;
#pragma unroll
        for (int n = 0; n < 64; ++n)
            cnt += (int)((((vals[n] ^ p) & himask) == 0u) && ((vals[n] & bit) != 0u));
        cnt += __shfl_xor(cnt, 1);
        cnt += __shfl_xor(cnt, 2);
        cnt += __shfl_xor(cnt, 4);
        cnt += __shfl_xor(cnt, 8);
        if (cnt >= kth) p |= bit; else kth -= cnt;
    }

    // build 1024-bit keep mask; val n is col = 256*(n>>4) + 16*(n&15) + jj
    unsigned long long wpart[16];
#pragma unroll
    for (int w = 0; w < 16; ++w) wpart[w] = 0ull;
#pragma unroll
    for (int n = 0; n < 64; ++n) {
        int w = ((n >> 4) << 2) + ((n & 15) >> 2);
        int bpos = ((n & 3) << 4) + jj;
        wpart[w] |= ((unsigned long long)(vals[n] >= p)) << bpos;
    }
#pragma unroll
    for (int s = 1; s < 16; s <<= 1) {
#pragma unroll
        for (int w = 0; w < 16; ++w)
            wpart[w] |= __shfl_xor(wpart[w], s);
    }
    mask[((size_t)h * 1024 + qrow) * 16 + jj] = wpart[jj];
}

// ---------------- MFMA flash attention, swapped QK^T -----------------------
#define ATTN_KP 136   // u16 pitch of K rows (272B)
#define ATTN_VP 40    // u16 pitch of vT rows (80B)

__global__ __launch_bounds__(256) void attn_mfma_kernel(
    const u16* __restrict__ qr,   // [32][1024][128], pre-scaled
    const u16* __restrict__ kr,   // [8][1024][128]
    const u16* __restrict__ vT,   // [8][128][1024]
    const unsigned long long* __restrict__ mask,
    u16* __restrict__ attn)       // [1024][4096]
{
    int bx = blockIdx.x;
    int qt = (bx & 1) ? (bx >> 1) : (15 - (bx >> 1));  // heavy/light interleave
    int h = blockIdx.y;
    int kvh = h >> 2;
    int q0 = qt * 64;
    int t = threadIdx.x;
    int wave = t >> 6, lane = t & 63;
    int fr = lane & 15, fq = lane >> 4;
    int qrow = q0 + wave * 16 + fr;

    __shared__ u16 Ks[32 * ATTN_KP];
    __shared__ u16 Vs[128 * ATTN_VP];

    bf16x8 qf[4];
    const u16* qbase = qr + ((size_t)h * 1024 + qrow) * 128 + fq * 8;
#pragma unroll
    for (int kc = 0; kc < 4; ++kc)
        qf[kc] = *(const bf16x8*)(qbase + kc * 32);

    float m_run = -3.0e38f, l_run = 0.f;
    f32x4 accO[8];
#pragma unroll
    for (int m2 = 0; m2 < 8; ++m2) accO[m2] = 0.f;

    const unsigned long long* mrow = mask + ((size_t)h * 1024 + qrow) * 16;
    const u16* kgh = kr + (size_t)kvh * 1024 * 128;
    const u16* vgh = vT + (size_t)kvh * 128 * 1024;

    int ntiles = (q0 + 64) >> 5;
    for (int c = 0; c < ntiles; ++c) {
        int kv0 = c * 32;
        __syncthreads();
#pragma unroll
        for (int u = 0; u < 2; ++u) {
            int e = t + u * 256;
            int row = e >> 4, bc = (e & 15) * 8;
            uint4 d4 = *(const uint4*)(kgh + ((size_t)(kv0 + row)) * 128 + bc);
            *(uint4*)(&Ks[row * ATTN_KP + bc]) = d4;
        }
#pragma unroll
        for (int u = 0; u < 2; ++u) {
            int e = t + u * 256;
            int row = e >> 2, bc = (e & 3) * 8;
            uint4 d4 = *(const uint4*)(vgh + (size_t)row * 1024 + kv0 + bc);
            *(uint4*)(&Vs[row * ATTN_VP + bc]) = d4;
        }
        __syncthreads();

        f32x4 accS[2];
        accS[0] = 0.f; accS[1] = 0.f;
#pragma unroll
        for (int t2 = 0; t2 < 2; ++t2)
#pragma unroll
            for (int kc = 0; kc < 4; ++kc) {
                bf16x8 kf = *(const bf16x8*)(&Ks[(t2 * 16 + fr) * ATTN_KP + kc * 32 + fq * 8]);
                accS[t2] = __builtin_amdgcn_mfma_f32_16x16x32_bf16(kf, qf[kc], accS[t2], 0, 0, 0);
            }

        unsigned long long mw = mrow[kv0 >> 6];
        int mshift = kv0 & 32;
        float p[2][4];
        float tmax = -3.0e38f;
#pragma unroll
        for (int t2 = 0; t2 < 2; ++t2)
#pragma unroll
            for (int j = 0; j < 4; ++j) {
                int kvi = (fq << 2) + (t2 << 4) + j;
                bool ok = ((mw >> (mshift + kvi)) & 1ull) && (kv0 + kvi <= qrow);
                float s = ok ? accS[t2][j] : -3.0e38f;
                p[t2][j] = s;
                tmax = fmaxf(tmax, s);
            }
        tmax = fmaxf(tmax, __shfl_xor(tmax, 16));
        tmax = fmaxf(tmax, __shfl_xor(tmax, 32));
        float m_new = fmaxf(m_run, tmax);
        float sf = __expf(m_run - m_new);
        float psum = 0.f;
#pragma unroll
        for (int t2 = 0; t2 < 2; ++t2)
#pragma unroll
            for (int j = 0; j < 4; ++j) {
                float e = (p[t2][j] > -1.0e38f) ? __expf(p[t2][j] - m_new) : 0.f;
                p[t2][j] = e;
                psum += e;
            }
        psum += __shfl_xor(psum, 16);
        psum += __shfl_xor(psum, 32);
        l_run = l_run * sf + psum;
        m_run = m_new;

#pragma unroll
        for (int m2 = 0; m2 < 8; ++m2) accO[m2] *= sf;

        unsigned W0, W1, W2, W3;
        asm("v_cvt_pk_bf16_f32 %0, %1, %2" : "=v"(W0) : "v"(p[0][0]), "v"(p[0][1]));
        asm("v_cvt_pk_bf16_f32 %0, %1, %2" : "=v"(W1) : "v"(p[0][2]), "v"(p[0][3]));
        asm("v_cvt_pk_bf16_f32 %0, %1, %2" : "=v"(W2) : "v"(p[1][0]), "v"(p[1][1]));
        asm("v_cvt_pk_bf16_f32 %0, %1, %2" : "=v"(W3) : "v"(p[1][2]), "v"(p[1][3]));
        int srcA = fr + ((fq & 1) << 5);
        int srcB = srcA + 16;
        unsigned a0 = __shfl(W0, srcA), a1 = __shfl(W1, srcA);
        unsigned a2 = __shfl(W2, srcA), a3 = __shfl(W3, srcA);
        unsigned b0 = __shfl(W0, srcB), b1 = __shfl(W1, srcB);
        unsigned b2 = __shfl(W2, srcB), b3 = __shfl(W3, srcB);
        bool hi = (fq & 2) != 0;
        union { uint4 u; bf16x8 b; } pc;
        pc.u.x = hi ? a2 : a0;
        pc.u.y = hi ? a3 : a1;
        pc.u.z = hi ? b2 : b0;
        pc.u.w = hi ? b3 : b1;

#pragma unroll
        for (int m2 = 0; m2 < 8; ++m2) {
            bf16x8 vf = *(const bf16x8*)(&Vs[(m2 * 16 + fr) * ATTN_VP + fq * 8]);
            accO[m2] = __builtin_amdgcn_mfma_f32_16x16x32_bf16(vf, pc.b, accO[m2], 0, 0, 0);
        }
    }

    float il = 1.0f / l_run;
    u16* obase = attn + (size_t)qrow * 4096 + h * 128 + fq * 4;
#pragma unroll
    for (int m2 = 0; m2 < 8; ++m2) {
        uint2 st;
        st.x = (unsigned)f2b(accO[m2][0] * il) | ((unsigned)f2b(accO[m2][1] * il) << 16);
        st.y = (unsigned)f2b(accO[m2][2] * il) | ((unsigned)f2b(accO[m2][3] * il) << 16);
        *(uint2*)(obase + m2 * 16) = st;
    }
}

extern "C" void kernel_launch(void* const* d_in, const int* in_sizes, int n_in,
                              void* d_out, int out_size, void* d_ws, size_t ws_size,
                              hipStream_t stream)
{
    (void)in_sizes; (void)n_in; (void)out_size; (void)ws_size;
    const float* hs   = (const float*)d_in[0];
    const float* wq   = (const float*)d_in[1];
    const float* wk   = (const float*)d_in[2];
    const float* wv   = (const float*)d_in[3];
    const float* wo   = (const float*)d_in[4];
    const float* mixq = (const float*)d_in[5];
    const float* mixk = (const float*)d_in[6];
    const float* qpos = (const float*)d_in[7];
    const float* kpos = (const float*)d_in[8];
    float* out = (float*)d_out;

    // workspace layout (time-aliased; high-water ~88 MB)
    float* ws   = (float*)d_ws;
    float* qb   = ws;                     // 4M f32
    float* kb   = qb + 4194304;           // 1M
    float* vb   = kb + 1048576;           // 1M
    float* pq   = vb + 1048576;           // 4M } phase1: wqT; phase2: pq;
    float* pk   = pq + 4194304;           // 4M } phase3: qr/kr/vT; phase4: woT
    float* lrq  = pk + 4194304;
    float* lrk  = lrq + 32768;
    float* cosb = lrk + 32768;
    float* sinb = cosb + 65536;
    unsigned long long* mask = (unsigned long long*)(sinb + 65536); // 512K u64
    u16* hs_bf = (u16*)(ws + 14876672 + 1048576);  // 4M u16 (later attn_bf)
    u16* wkT   = hs_bf + 4194304;                  // 4M u16
    u16* wvT   = wkT + 4194304;                    // 4M u16
    u16* wqT   = (u16*)pq;                         // 16M u16 (alias, phase1)
    u16* woT   = (u16*)pq;                         // 16M u16 (alias, phase4)
    u16* qr_bf = (u16*)pq;                         // 4M u16 (alias, phase3)
    u16* kr_bf = (u16*)pk;                         // 1M u16 (alias, phase3)
    u16* vT_bf = (u16*)(pk + 1048576);             // 1M u16 (alias, phase3)
    u16* attn_bf = hs_bf;                          // alias (hs_bf dead by then)

    hipLaunchKernelGGL(rope_tables_kernel, dim3(1024), dim3(64), 0, stream, cosb, sinb);
    hipLaunchKernelGGL(conv_bf16_kernel, dim3(4096), dim3(256), 0, stream, hs, hs_bf);
    hipLaunchKernelGGL(transpose_bf16_kernel, dim3(64, 64), dim3(256), 0, stream, wq, wqT, 4096, 4096);
    hipLaunchKernelGGL(transpose_bf16_kernel, dim3(16, 64), dim3(256), 0, stream, wk, wkT, 4096, 1024);
    hipLaunchKernelGGL(transpose_bf16_kernel, dim3(16, 64), dim3(256), 0, stream, wv, wvT, 4096, 1024);
    hipLaunchKernelGGL(gemm_qkv_bf16_kernel, dim3(48, 8), dim3(256), 0, stream,
                       hs_bf, wqT, wkT, wvT, qb, kb, vb);
    hipLaunchKernelGGL(lr_kernel, dim3(1024), dim3(256), 0, stream, hs, mixq, mixk, lrq, lrk);
    hipLaunchKernelGGL(ppos_kernel, dim3(32, 1024), dim3(128), 0, stream, lrq, qpos, pq);
    hipLaunchKernelGGL(ppos_kernel, dim3(32, 1024), dim3(128), 0, stream, lrk, kpos, pk);
    hipLaunchKernelGGL(draft_select_kernel, dim3(64, 32), dim3(256), 0, stream, pq, pk, mask);
    // pq/pk now dead -> reuse for RoPE'd bf16 q/k and transposed v
    hipLaunchKernelGGL(rope_pack_kernel, dim3(1024, 32), dim3(128), 0, stream,
                       qb, 4096, cosb, sinb, qr_bf, 0.08838834764831845f);
    hipLaunchKernelGGL(rope_pack_kernel, dim3(1024, 8), dim3(128), 0, stream,
                       kb, 1024, cosb, sinb, kr_bf, 1.0f);
    hipLaunchKernelGGL(transpose_bf16_kernel, dim3(16, 16), dim3(256), 0, stream, vb, vT_bf, 1024, 1024);
    hipLaunchKernelGGL(attn_mfma_kernel, dim3(16, 32), dim3(256), 0, stream,
                       qr_bf, kr_bf, vT_bf, mask, attn_bf);
    hipLaunchKernelGGL(transpose_bf16_kernel, dim3(64, 64), dim3(256), 0, stream, wo, woT, 4096, 4096);
    hipLaunchKernelGGL(gemm_wo_bf16_kernel, dim3(32, 8), dim3(256), 0, stream,
                       attn_bf, woT, out);
}